// Round 1
// baseline (174.816 us; speedup 1.0000x reference)
//
#include <hip/hip_runtime.h>
#include <hip/hip_bf16.h>

#define B_   16
#define T_   128
#define IN_  1024
#define H_   4096
#define OUT_ 1024
#define M_   (B_ * T_)   // 2048 rows = (b*T + t)

typedef __attribute__((ext_vector_type(8))) short short8;
typedef __attribute__((ext_vector_type(4))) float f32x4;
typedef __attribute__((ext_vector_type(4))) int i32x4;
typedef __attribute__((ext_vector_type(4))) unsigned short u16x4;
typedef unsigned short u16;
typedef signed char i8;

// ---------- helpers ----------
__device__ inline u16 f2bf_rne(float f) {
  unsigned u = __float_as_uint(f);
  unsigned r = u + 0x7FFFu + ((u >> 16) & 1u);
  return (u16)(r >> 16);
}
__device__ inline float bf2f(u16 s) {
  return __uint_as_float(((unsigned)s) << 16);
}
__device__ inline int pack4(int a, int b, int c, int d) {
  return (a & 255) | ((b & 255) << 8) | ((c & 255) << 16) | ((d & 255) << 24);
}

// XCD-aware 2D-chunked bijective swizzle (T1) for the 512-block gemm1 grid.
__device__ inline void xcd_swizzle(int bid0, int& bnI, int& bmI) {
  const int xcd = bid0 & 7;
  const int loc = bid0 >> 3;           // 0..63 within XCD
  bnI = (xcd & 3) * 8 + (loc & 7);
  bmI = (xcd >> 2) * 8 + (loc >> 3);
}

#define NX_  (M_ * IN_)
#define NW1_ (H_ * IN_)
#define NW2_ (H_ * H_)

__device__ inline void split4bf(const float4 f, u16* __restrict__ hi,
                                u16* __restrict__ lo, size_t e) {
  u16x4 h, l;
  h.x = f2bf_rne(f.x); l.x = f2bf_rne(f.x - bf2f(h.x));
  h.y = f2bf_rne(f.y); l.y = f2bf_rne(f.y - bf2f(h.y));
  h.z = f2bf_rne(f.z); l.z = f2bf_rne(f.z - bf2f(h.z));
  h.w = f2bf_rne(f.w); l.w = f2bf_rne(f.w - bf2f(h.w));
  *(u16x4*)(hi + e) = h;
  *(u16x4*)(lo + e) = l;
}

__device__ inline void splitw2_1(float w, int& c0, int& c1, int& c2) {
  int wf = __float2int_rn(w * 268435456.0f);  // 2^28 (exact: wf == c0<<16 + c1<<8 + c2)
  c0 = (wf + 32768) >> 16;
  int r0 = wf - (c0 << 16);
  if (r0 >= 32640) { c0 += 1; r0 -= 65536; }
  c1 = (r0 + 128) >> 8;
  c2 = r0 - (c1 << 8);
}

// ---------- split x, w1 only (w2 split is woven into gemm1) ----------
__global__ void split_xw1_kernel(const float4* __restrict__ x,
                                 const float4* __restrict__ w1,
                                 u16* __restrict__ xh, u16* __restrict__ xl,
                                 u16* __restrict__ w1h, u16* __restrict__ w1l) {
  const int total4 = (NX_ + NW1_) / 4;
  for (int i = blockIdx.x * blockDim.x + threadIdx.x; i < total4;
       i += gridDim.x * blockDim.x) {
    if (i < NX_ / 4) {
      split4bf(x[i], xh, xl, (size_t)i * 4);
    } else {
      int j = i - NX_ / 4;
      split4bf(w1[j], w1h, w1l, (size_t)j * 4);
    }
  }
}

// ---------- GEMM1: FUSED 4-combo bf16 (16x16x32, BK=64) + rec1 -> s1 (i8) ----------
// (unchanged this round — gemm2 is the bottleneck; isolate one structural change)
#define BK1 64

__global__ __launch_bounds__(256, 2) void gemm1_rec(
    const u16* __restrict__ Ah, const u16* __restrict__ Al,
    const u16* __restrict__ Bh, const u16* __restrict__ Bl,
    const float* __restrict__ bias, i8* __restrict__ s1out,
    const float4* __restrict__ w2src,
    i8* __restrict__ p0, i8* __restrict__ p1, i8* __restrict__ p2) {
  __shared__ __align__(16) char smem[65536];   // sAh|sAl|sBh|sBl 16K each; epilogue reuses [0,32K)
  u16* sAh = (u16*)smem;
  u16* sAl = (u16*)(smem + 16384);
  u16* sBh = (u16*)(smem + 32768);
  u16* sBl = (u16*)(smem + 49152);

  const int tid  = threadIdx.x;
  const int lane = tid & 63;
  const int wid  = tid >> 6;
  const int wm   = (wid >> 1) * 64;
  const int wn   = (wid & 1) * 64;
  const int bid  = blockIdx.y * 32 + blockIdx.x;   // flat id: w2-slice owner
  int bnI, bmI;
  xcd_swizzle(bid, bnI, bmI);
  const int bm = bmI * 128;
  const int bn = bnI * 128;

  const int sdst = (tid & 7) * 8;                          // linear LDS dest slot (elems)
  const int scol = (((tid & 7) ^ ((tid >> 3) & 7)) * 8);   // inverse-swizzled src col
  const int q8   = (lane >> 4) * 8;
  const int rsw  = (lane & 7) * 8;                         // row&7 == lane&7 swizzle

  f32x4 acc[4][4];
#pragma unroll
  for (int i = 0; i < 4; ++i)
#pragma unroll
    for (int j = 0; j < 4; ++j) acc[i][j] = (f32x4){0.f, 0.f, 0.f, 0.f};

  // woven-split pipeline prologue: tile 0's slice into regs
  const int wbase = bid * 8192 + tid * 2;
  float4 wfa = w2src[wbase];
  float4 wfb = w2src[wbase + 1];

#pragma unroll 1
  for (int it = 0; it < IN_ / BK1; ++it) {   // 16 k-tiles
    const int kt = it * BK1;
    __syncthreads();   // bar1: wf prefetch + stores from prev iter long done
#pragma unroll
    for (int l = 0; l < 4; ++l) {
      int row = l * 32 + (tid >> 3);
      size_t ga = (size_t)(bm + row) * IN_ + kt + scol;
      size_t gb = (size_t)(bn + row) * IN_ + kt + scol;
      int ld = row * BK1 + sdst;
      __builtin_amdgcn_global_load_lds(
          (const __attribute__((address_space(1))) unsigned int*)(Ah + ga),
          (__attribute__((address_space(3))) unsigned int*)(&sAh[ld]), 16, 0, 0);
      __builtin_amdgcn_global_load_lds(
          (const __attribute__((address_space(1))) unsigned int*)(Al + ga),
          (__attribute__((address_space(3))) unsigned int*)(&sAl[ld]), 16, 0, 0);
      __builtin_amdgcn_global_load_lds(
          (const __attribute__((address_space(1))) unsigned int*)(Bh + gb),
          (__attribute__((address_space(3))) unsigned int*)(&sBh[ld]), 16, 0, 0);
      __builtin_amdgcn_global_load_lds(
          (const __attribute__((address_space(1))) unsigned int*)(Bl + gb),
          (__attribute__((address_space(3))) unsigned int*)(&sBl[ld]), 16, 0, 0);
    }
    __syncthreads();   // bar2: drains ONLY L2-resident staging loads now

    // prefetch NEXT tile's wf slice (covered by the MFMA phase below)
    const int nit = (it + 1 < 16) ? it + 1 : 15;
    float4 nfa = w2src[wbase + nit * 512];
    float4 nfb = w2src[wbase + nit * 512 + 1];

    // convert + store CURRENT tile's wf (independent of MFMA; drains in bg)
    {
      const int sbase = bid * 8192 + it * 512 + tid * 2;
#pragma unroll
      for (int u = 0; u < 2; ++u) {
        float4 f = u ? wfb : wfa;
        int a0, a1, a2, b0, b1, b2, c0, c1, c2, d0, d1, d2;
        splitw2_1(f.x, a0, a1, a2);
        splitw2_1(f.y, b0, b1, b2);
        splitw2_1(f.z, c0, c1, c2);
        splitw2_1(f.w, d0, d1, d2);
        size_t e = (size_t)(sbase + u) * 4;
        *(int*)(p0 + e) = pack4(a0, b0, c0, d0);
        *(int*)(p1 + e) = pack4(a1, b1, c1, d1);
        *(int*)(p2 + e) = pack4(a2, b2, c2, d2);
      }
    }

#pragma unroll
    for (int ks = 0; ks < BK1; ks += 32) {
      const int swz = (ks + q8) ^ rsw;
      short8 ah[4], al[4], bh[4], bl[4];
#pragma unroll
      for (int i = 0; i < 4; ++i) {
        int ro = (wm + i * 16 + (lane & 15)) * BK1 + swz;
        ah[i] = *(const short8*)&sAh[ro];
        al[i] = *(const short8*)&sAl[ro];
      }
#pragma unroll
      for (int j = 0; j < 4; ++j) {
        int ro = (wn + j * 16 + (lane & 15)) * BK1 + swz;
        bh[j] = *(const short8*)&sBh[ro];
        bl[j] = *(const short8*)&sBl[ro];
      }
#pragma unroll
      for (int i = 0; i < 4; ++i)
#pragma unroll
        for (int j = 0; j < 4; ++j) {
          acc[i][j] = __builtin_amdgcn_mfma_f32_16x16x32_bf16(ah[i], bh[j], acc[i][j], 0, 0, 0);
          acc[i][j] = __builtin_amdgcn_mfma_f32_16x16x32_bf16(ah[i], bl[j], acc[i][j], 0, 0, 0);
          acc[i][j] = __builtin_amdgcn_mfma_f32_16x16x32_bf16(al[i], bh[j], acc[i][j], 0, 0, 0);
          acc[i][j] = __builtin_amdgcn_mfma_f32_16x16x32_bf16(al[i], bl[j], acc[i][j], 0, 0, 0);
        }
    }

    wfa = nfa;
    wfb = nfb;
  }

  // ---- epilogue: two-half LDS staging (32 KB) + LIF t-scan, s1 as i8 ----
  float* hl = (float*)smem;               // [64][128]
  const int c = tid & 127;
  const float bv = bias[bn + c];
  float v = 0.0f;
  __syncthreads();
#pragma unroll
  for (int half = 0; half < 2; ++half) {
    if (wm == half * 64) {
#pragma unroll
      for (int i = 0; i < 4; ++i)
#pragma unroll
        for (int j = 0; j < 4; ++j) {
          int col = wn + j * 16 + (lane & 15);
#pragma unroll
          for (int r = 0; r < 4; ++r) {
            int lrow = i * 16 + (lane >> 4) * 4 + r;
            hl[lrow * 128 + col] = acc[i][j][r];
          }
        }
    }
    __syncthreads();
    if (tid < 128) {
      for (int tt = 0; tt < 64; ++tt) {
        float h = hl[tt * 128 + c] + bv;
        v = 0.9f * v + h;
        i8 sp = 0;
        if (v > 1.0f) { sp = 1; v -= 1.0f; }
        s1out[(size_t)(bm + half * 64 + tt) * H_ + bn + c] = sp;
      }
    }
    __syncthreads();
  }
}

// ---------- GEMM2: i8 3-plane, single merged K-loop, 8-wave 3-phase counted-vmcnt ----------
// R14: T3+T4+T5 port. BM=256, BN=128, BK=64, 512 threads (8 waves, 4Mx2N, 64x64/wave).
// LDS 80KB dbuf (1 block/CU): per 40KB buffer: A[128 pairs][128B] 16K |
// P1 8K | P2 8K | P0 8K (each [64 pairs][128B], paired-row XOR swizzle).
// Per k-tile: 3 phases (c1/c2/c0), each {ds_read ∥ prefetch-issue, s_barrier,
// lgkmcnt(0), setprio(1)+16 MFMA+setprio(0), s_barrier}; counted vmcnt(5)
// only at end of phases 1 and 3 (prefetch depth = 1.5 tiles: h0={A,P1},
// h1={P2,P0}; tail staging is clamped so counts stay uniform).
// Math identical to R13: acc = 2^-28*(Σc1<<8 + Σc2) + 2^-12*Σc0, exact ints.
#define G2_OFFP1 16384
#define G2_OFFP2 24576
#define G2_OFFP0 32768
#define G2_BUFS  40960

#define G2_GLD(srcp, ldsp)                                                  \
  __builtin_amdgcn_global_load_lds(                                         \
      (const __attribute__((address_space(1))) unsigned int*)(srcp),        \
      (__attribute__((address_space(3))) unsigned int*)(ldsp), 16, 0, 0)

__global__ __launch_bounds__(512, 2) void gemm2_i8(
    const i8* __restrict__ A,
    const i8* __restrict__ P0, const i8* __restrict__ P1,
    const i8* __restrict__ P2,
    const float* __restrict__ bias, float* __restrict__ s2out) {
  __shared__ __align__(16) char smem[81920];

  const int tid  = threadIdx.x;
  const int lane = tid & 63;
  const int wid  = tid >> 6;           // 0..7
  const int wm   = (wid >> 1) * 64;    // 0,64,128,192
  const int wn   = (wid & 1) * 64;     // 0,64

  // bijective XCD swizzle: 8 bmI x 32 bnI grid, 2x16 chunk per XCD
  const int bid = blockIdx.x;
  const int xcd = bid & 7, loc = bid >> 3;          // loc 0..31
  const int bmI = (xcd & 3) * 2 + (loc & 1);        // 0..7
  const int bnI = (xcd >> 2) * 16 + (loc >> 1);     // 0..31
  const int bm = bmI * 256, bn = bnI * 128;

  // ---- staging addressing (lane-linear LDS dest + inverse-swizzled global src) ----
  const int j8   = tid & 7;
  const int r8   = tid >> 3;                 // pair index 0..63
  const int cc   = j8 ^ (r8 & 7);            // inverse swizzle chunk
  const int srow = 2 * r8 + (cc >> 2);       // global row within tile (0..127)
  const int scol = (cc & 3) * 16;            // byte chunk within 64B k-range
  const int dst0 = r8 * 128 + j8 * 16;       // lane-linear: = wave*1024 + lane*16
  const size_t gA = (size_t)(bm + srow) * H_ + scol;   // + l*128*H_ + kt
  const size_t gP = (size_t)(bn + srow) * H_ + scol;   // + kt

  // ---- fragment-read addressing (swizzled, conflict-free ds_read_b128) ----
  const int r15 = lane & 15, qk = lane >> 4;
  const int lro = (r15 >> 1) * 128 +
                  (((((r15 & 1) << 2) + qk) ^ ((r15 >> 1) & 7)) * 16);
  const int abase = wm * 64 + lro;   // + i*1024 within A region (16KB)
  const int bbase = wn * 64 + lro;   // + j*1024 within plane region (8KB)

  i32x4 acc0[4][4], acc1[4][4], acc2[4][4];
#pragma unroll
  for (int i = 0; i < 4; ++i)
#pragma unroll
    for (int j = 0; j < 4; ++j) {
      acc0[i][j] = (i32x4){0, 0, 0, 0};
      acc1[i][j] = (i32x4){0, 0, 0, 0};
      acc2[i][j] = (i32x4){0, 0, 0, 0};
    }

  // ---- prologue: h0(0), h1(0), h0(1) ----
  G2_GLD(A + gA, smem + dst0);
  G2_GLD(A + gA + (size_t)128 * H_, smem + 8192 + dst0);
  G2_GLD(P1 + gP, smem + G2_OFFP1 + dst0);
  G2_GLD(P2 + gP, smem + G2_OFFP2 + dst0);
  G2_GLD(P0 + gP, smem + G2_OFFP0 + dst0);
  G2_GLD(A + gA + 64, smem + G2_BUFS + dst0);
  G2_GLD(A + gA + (size_t)128 * H_ + 64, smem + G2_BUFS + 8192 + dst0);
  G2_GLD(P1 + gP + 64, smem + G2_BUFS + G2_OFFP1 + dst0);
  asm volatile("s_waitcnt vmcnt(5)" ::: "memory");   // h0(0) done
  __builtin_amdgcn_s_barrier();

#pragma unroll 1
  for (int t = 0; t < 64; ++t) {
    char* cur = smem + (t & 1) * G2_BUFS;
    char* nxt = smem + ((t + 1) & 1) * G2_BUFS;
    const int kt1 = (t < 63 ? t + 1 : 63) << 6;
    const int kt2 = (t < 62 ? t + 2 : 63) << 6;

    i32x4 a[4], b[4];

    // ======== phase 1: plane c1 (reads A+P1 = h0(t); prefetch h1(t+1)) ========
#pragma unroll
    for (int i = 0; i < 4; ++i)
      a[i] = *(const i32x4*)(cur + abase + i * 1024);
#pragma unroll
    for (int j = 0; j < 4; ++j)
      b[j] = *(const i32x4*)(cur + G2_OFFP1 + bbase + j * 1024);
    G2_GLD(P2 + gP + kt1, nxt + G2_OFFP2 + dst0);
    G2_GLD(P0 + gP + kt1, nxt + G2_OFFP0 + dst0);
    __builtin_amdgcn_s_barrier();
    asm volatile("s_waitcnt lgkmcnt(0)" ::: "memory");
    __builtin_amdgcn_s_setprio(1);
#pragma unroll
    for (int i = 0; i < 4; ++i)
#pragma unroll
      for (int j = 0; j < 4; ++j)
        acc1[i][j] = __builtin_amdgcn_mfma_i32_16x16x64_i8(a[i], b[j], acc1[i][j], 0, 0, 0);
    __builtin_amdgcn_s_setprio(0);
    asm volatile("s_waitcnt vmcnt(5)" ::: "memory");   // h1(t) done
    __builtin_amdgcn_s_barrier();

    // ======== phase 2: plane c2 (reads P2 = h1(t); prefetch h0(t+2)) ========
#pragma unroll
    for (int j = 0; j < 4; ++j)
      b[j] = *(const i32x4*)(cur + G2_OFFP2 + bbase + j * 1024);
    G2_GLD(A + gA + kt2, cur + dst0);
    G2_GLD(A + gA + (size_t)128 * H_ + kt2, cur + 8192 + dst0);
    G2_GLD(P1 + gP + kt2, cur + G2_OFFP1 + dst0);
    __builtin_amdgcn_s_barrier();
    asm volatile("s_waitcnt lgkmcnt(0)" ::: "memory");
    __builtin_amdgcn_s_setprio(1);
#pragma unroll
    for (int i = 0; i < 4; ++i)
#pragma unroll
      for (int j = 0; j < 4; ++j)
        acc2[i][j] = __builtin_amdgcn_mfma_i32_16x16x64_i8(a[i], b[j], acc2[i][j], 0, 0, 0);
    __builtin_amdgcn_s_setprio(0);
    __builtin_amdgcn_s_barrier();

    // ======== phase 3: plane c0 (reads P0 = h1(t)) ========
#pragma unroll
    for (int j = 0; j < 4; ++j)
      b[j] = *(const i32x4*)(cur + G2_OFFP0 + bbase + j * 1024);
    __builtin_amdgcn_s_barrier();
    asm volatile("s_waitcnt lgkmcnt(0)" ::: "memory");
    __builtin_amdgcn_s_setprio(1);
#pragma unroll
    for (int i = 0; i < 4; ++i)
#pragma unroll
      for (int j = 0; j < 4; ++j)
        acc0[i][j] = __builtin_amdgcn_mfma_i32_16x16x64_i8(a[i], b[j], acc0[i][j], 0, 0, 0);
    __builtin_amdgcn_s_setprio(0);
    asm volatile("s_waitcnt vmcnt(5)" ::: "memory");   // h0(t+1) done
    __builtin_amdgcn_s_barrier();
  }

  // ---- epilogue: drain strays, 4-quarter staging + LIF t-scan (2 batches) ----
  float* hl = (float*)smem;               // [64][128]
  const int ec = tid & 127;
  const float bv = bias[bn + ec];
  asm volatile("s_waitcnt vmcnt(0)" ::: "memory");   // clamped tail loads
  __syncthreads();
#pragma unroll
  for (int hb = 0; hb < 2; ++hb) {        // batch = 2*bmI + hb
    float v = 0.0f, cnt = 0.0f;
#pragma unroll
    for (int half = 0; half < 2; ++half) {
      const int hq = hb * 2 + half;       // quarter 0..3 (rows hq*64..+63)
      if (wm == hq * 64) {
#pragma unroll
        for (int i = 0; i < 4; ++i)
#pragma unroll
          for (int j = 0; j < 4; ++j) {
            int col = wn + j * 16 + (lane & 15);
#pragma unroll
            for (int r = 0; r < 4; ++r) {
              int lrow = i * 16 + (lane >> 4) * 4 + r;
              float val = 0x1p-28f * (float)((acc1[i][j][r] << 8) + acc2[i][j][r]) +
                          0x1p-12f * (float)acc0[i][j][r];
              hl[lrow * 128 + col] = val;
            }
          }
      }
      __syncthreads();
      if (tid < 128) {
        for (int tt = 0; tt < 64; ++tt) {
          float h = hl[tt * 128 + ec] + bv;
          v = 0.9f * v + h;
          if (v > 1.0f) { cnt += 1.0f; v -= 1.0f; }
        }
      }
      __syncthreads();
    }
    if (tid < 128) s2out[(size_t)(2 * bmI + hb) * H_ + bn + ec] = cnt;
  }
}

// ---------- readout: out[b,o] = s2sum[b,:] . w3[o,:] + T*b3[o] ----------
__global__ void out_gemm_kernel(const float* __restrict__ s2sum,
                                const float* __restrict__ w3,
                                const float* __restrict__ b3,
                                float* __restrict__ out) {
  int o = blockIdx.x;
  int lane = threadIdx.x;
  float acc[B_];
#pragma unroll
  for (int b = 0; b < B_; ++b) acc[b] = 0.f;
  const float* wrow = w3 + (size_t)o * H_;
  for (int i = 0; i < H_ / 64; ++i) {
    float w = wrow[i * 64 + lane];
#pragma unroll
    for (int b = 0; b < B_; ++b)
      acc[b] += w * s2sum[b * H_ + i * 64 + lane];
  }
#pragma unroll
  for (int b = 0; b < B_; ++b) {
    float v = acc[b];
#pragma unroll
    for (int off = 32; off > 0; off >>= 1) v += __shfl_xor(v, off);
    if (lane == b) out[b * OUT_ + o] = v + (float)T_ * b3[o];
  }
}

// ---------- launch ----------
extern "C" void kernel_launch(void* const* d_in, const int* in_sizes, int n_in,
                              void* d_out, int out_size, void* d_ws, size_t ws_size,
                              hipStream_t stream) {
  const float* x  = (const float*)d_in[0];
  const float* w1 = (const float*)d_in[1];
  const float* b1 = (const float*)d_in[2];
  const float* w2 = (const float*)d_in[3];
  const float* b2 = (const float*)d_in[4];
  const float* w3 = (const float*)d_in[5];
  const float* b3 = (const float*)d_in[6];
  float* out = (float*)d_out;

  // workspace (80.25 MiB):
  //   [0,8M) s1 i8 | [8M,12M) x_hi | [12M,16M) x_lo | [16M,24M) w1_hi
  //   [24M,32M) w1_lo | [32M,48M) w2p0 | [48M,64M) w2p1 | [64M,80M) w2p2
  //   [80M,+256K) s2sum
  char* ws = (char*)d_ws;
  i8*    s1    = (i8*)(ws);
  u16*   x_hi  = (u16*)(ws + 8388608);
  u16*   x_lo  = (u16*)(ws + 12582912);
  u16*   w1_hi = (u16*)(ws + 16777216);
  u16*   w1_lo = (u16*)(ws + 25165824);
  i8*    w2p0  = (i8*)(ws + 33554432);
  i8*    w2p1  = (i8*)(ws + 50331648);
  i8*    w2p2  = (i8*)(ws + 67108864);
  float* s2sum = (float*)(ws + 83886080);

  // 1) split x, w1 only (48 MB traffic, ~8 us)
  split_xw1_kernel<<<1024, 256, 0, stream>>>((const float4*)x, (const float4*)w1,
                                             x_hi, x_lo, w1_hi, w1_lo);

  dim3 g1(H_ / 128, M_ / 128);  // (32, 16) = 512 blocks
  // 2) GEMM1 + fused rec1 + pipelined woven w2 split, XCD-swizzled
  gemm1_rec<<<g1, 256, 0, stream>>>(x_hi, x_lo, w1_hi, w1_lo, b1, s1,
                                    (const float4*)w2, w2p0, w2p1, w2p2);

  // 3) GEMM2 + fused rec2: 8-wave 3-phase counted-vmcnt schedule
  gemm2_i8<<<dim3(256), 512, 0, stream>>>(s1, w2p0, w2p1, w2p2, b2, s2sum);

  // 4) readout
  out_gemm_kernel<<<OUT_, 64, 0, stream>>>(s2sum, w3, b3, out);
}